// Round 2
// baseline (203.499 us; speedup 1.0000x reference)
//
#include <hip/hip_runtime.h>

typedef __attribute__((ext_vector_type(8))) short bf16x8;
typedef __attribute__((ext_vector_type(4))) float f32x4;
typedef __attribute__((ext_vector_type(8))) unsigned short u16x8;

#define NT 26
#define BROWS 32
#define NKS 16            // k-steps of 32 over the 512-wide (padded) cat block
#define LDSTR 520         // bf16 elems per LDS row (508 cat + 4 zero + 8 slack)
#define HSTR 36           // fp32 h row stride (dwords)
#define Z1STR 68          // fp32 z1 row stride (dwords)

__constant__ int c_OFFS[NT] = {
    0,1000001,1500002,1600003,1650004,1660005,1670006,1675007,1680008,1681009,
    1682010,1682511,1683012,1683113,1683214,1683265,1683316,1683337,1683358,
    1683369,1683380,1683386,1683392,1683396,1683400,1683403};
__constant__ int c_DIMS[NT] = {
    32,32,32,32,32,32,32,32,32,32,32,32,21,21,14,14,9,9,6,6,4,4,4,4,4,4};
__constant__ int c_COLF[NT] = {
    0,32,64,96,128,160,192,224,256,288,320,352,384,405,426,440,454,463,
    472,478,484,488,492,496,500,504};

__device__ __forceinline__ unsigned short f2bf(float f) {
  unsigned int u = __builtin_bit_cast(unsigned int, f);
  u += 0x7fffu + ((u >> 16) & 1u);       // RNE
  return (unsigned short)(u >> 16);
}

__device__ __forceinline__ float silu_f(float x) {
  return x / (1.0f + __expf(-x));
}

__device__ __forceinline__ void gather_one(const float* __restrict__ emb,
                                           unsigned short* __restrict__ fused,
                                           int p, int idx) {
  const int i = p >> 5;          // table id (wave-uniform by construction)
  const int r = p & 31;          // batch row within tile
  const float* src = emb + (size_t)(c_OFFS[i] + idx) * 32;
  unsigned short* dst = &fused[r * LDSTR + c_COLF[i]];
  const int d = c_DIMS[i];
  if (d == 32) {
    const float4* s4 = (const float4*)src;
    const float4 f0 = s4[0], f1 = s4[1], f2 = s4[2], f3 = s4[3];
    const float4 f4 = s4[4], f5 = s4[5], f6 = s4[6], f7 = s4[7];
    u16x8 o0, o1, o2, o3;
    o0[0]=f2bf(f0.x); o0[1]=f2bf(f0.y); o0[2]=f2bf(f0.z); o0[3]=f2bf(f0.w);
    o0[4]=f2bf(f1.x); o0[5]=f2bf(f1.y); o0[6]=f2bf(f1.z); o0[7]=f2bf(f1.w);
    o1[0]=f2bf(f2.x); o1[1]=f2bf(f2.y); o1[2]=f2bf(f2.z); o1[3]=f2bf(f2.w);
    o1[4]=f2bf(f3.x); o1[5]=f2bf(f3.y); o1[6]=f2bf(f3.z); o1[7]=f2bf(f3.w);
    o2[0]=f2bf(f4.x); o2[1]=f2bf(f4.y); o2[2]=f2bf(f4.z); o2[3]=f2bf(f4.w);
    o2[4]=f2bf(f5.x); o2[5]=f2bf(f5.y); o2[6]=f2bf(f5.z); o2[7]=f2bf(f5.w);
    o3[0]=f2bf(f6.x); o3[1]=f2bf(f6.y); o3[2]=f2bf(f6.z); o3[3]=f2bf(f6.w);
    o3[4]=f2bf(f7.x); o3[5]=f2bf(f7.y); o3[6]=f2bf(f7.z); o3[7]=f2bf(f7.w);
    u16x8* d8 = (u16x8*)dst;     // COLF even for d==32 tables; 1040B row stride
    d8[0] = o0; d8[1] = o1; d8[2] = o2; d8[3] = o3;
  } else {
    #pragma unroll 4
    for (int c = 0; c < d; ++c) dst[c] = f2bf(src[c]);
  }
}

extern "C" __global__ void __launch_bounds__(256, 4)
tab_fused(const float* __restrict__ xc,   // [B,64]
          const int* __restrict__ xcat,   // [B,26]
          const float* __restrict__ emb,  // [TOTAL_ROWS,32]
          const float* __restrict__ Wc,   // [64,32]
          const float* __restrict__ bc,   // [32]
          const float* __restrict__ lng,  // [32]
          const float* __restrict__ lnb,  // [32]
          const float* __restrict__ W1,   // [540,64]
          const float* __restrict__ b1,   // [64]
          const float* __restrict__ W2,   // [64,32]
          const float* __restrict__ b2,   // [32]
          float* __restrict__ out) {      // [B,32]
  // cat tile (bf16) lives here during phases 1-2; z1 (fp32) aliases it after.
  __shared__ __attribute__((aligned(16))) float smem[(BROWS * LDSTR) / 2]; // 33,280 B
  __shared__ __attribute__((aligned(16))) float hf[BROWS * HSTR];          //  4,608 B
  unsigned short* fused = (unsigned short*)smem;
  float* z1 = smem;

  const int t  = threadIdx.x;
  const int w  = t >> 6;          // wave id 0..3
  const int l  = t & 63;          // lane
  const int R0 = blockIdx.x * BROWS;

  // ---------------- phase 0: stage W1[32:544] bf16 B-fragments ----------------
  const int bn = (w << 4) + (l & 15);   // z1 column owned by this lane
  const int kg = (l >> 4) << 3;         // k sub-offset 0/8/16/24 within a k-step
  bf16x8 bfw[NKS];
  #pragma unroll
  for (int ks = 0; ks < NKS; ++ks) {
    #pragma unroll
    for (int j = 0; j < 8; ++j) {
      const int k = 32 + (ks << 5) + kg + j;   // global W1 row
      const float v = (k < 540) ? W1[k * 64 + bn] : 0.0f;
      bfw[ks][j] = (short)f2bf(v);
    }
  }
  // zero pad cols 508..511 (one 8B write per row)
  if (t < BROWS) *(unsigned long long*)&fused[t * LDSTR + 508] = 0ull;

  // ---------------- phase 1a: gather (all 256 threads, table-major) -----------
  // p = i*32 + r: each wave-iteration covers exactly 2 equal-width tables.
  int pidx[4];
  #pragma unroll
  for (int it = 0; it < 3; ++it) {
    const int p = t + it * 256;
    pidx[it] = xcat[(size_t)(R0 + (p & 31)) * NT + (p >> 5)];
  }
  if (t < 64) pidx[3] = xcat[(size_t)(R0 + (t & 31)) * NT + ((t + 768) >> 5)];
  #pragma unroll
  for (int it = 0; it < 3; ++it) gather_one(emb, fused, t + it * 256, pidx[it]);
  if (t < 64) gather_one(emb, fused, t + 768, pidx[3]);

  // ---------------- phase 1b: cont MLP, 8 threads per row ---------------------
  {
    const int r  = t >> 3;
    const int j0 = (t & 7) << 2;
    const float* xr = xc + (size_t)(R0 + r) * 64;
    float h0 = bc[j0], h1 = bc[j0 + 1], h2 = bc[j0 + 2], h3 = bc[j0 + 3];
    #pragma unroll 4
    for (int k4 = 0; k4 < 16; ++k4) {
      const float4 x4 = ((const float4*)xr)[k4];
      const float* wb = Wc + (k4 * 4) * 32 + j0;
      const float4 w0 = *(const float4*)(wb);
      const float4 w1 = *(const float4*)(wb + 32);
      const float4 w2 = *(const float4*)(wb + 64);
      const float4 w3 = *(const float4*)(wb + 96);
      h0 = __fmaf_rn(x4.x, w0.x, h0); h1 = __fmaf_rn(x4.x, w0.y, h1);
      h2 = __fmaf_rn(x4.x, w0.z, h2); h3 = __fmaf_rn(x4.x, w0.w, h3);
      h0 = __fmaf_rn(x4.y, w1.x, h0); h1 = __fmaf_rn(x4.y, w1.y, h1);
      h2 = __fmaf_rn(x4.y, w1.z, h2); h3 = __fmaf_rn(x4.y, w1.w, h3);
      h0 = __fmaf_rn(x4.z, w2.x, h0); h1 = __fmaf_rn(x4.z, w2.y, h1);
      h2 = __fmaf_rn(x4.z, w2.z, h2); h3 = __fmaf_rn(x4.z, w2.w, h3);
      h0 = __fmaf_rn(x4.w, w3.x, h0); h1 = __fmaf_rn(x4.w, w3.y, h1);
      h2 = __fmaf_rn(x4.w, w3.z, h2); h3 = __fmaf_rn(x4.w, w3.w, h3);
    }
    // LayerNorm over the 8-lane group holding this row's 32 outputs
    float s1 = h0 + h1 + h2 + h3;
    float s2 = h0 * h0 + h1 * h1 + h2 * h2 + h3 * h3;
    #pragma unroll
    for (int m = 1; m < 8; m <<= 1) {
      s1 += __shfl_xor(s1, m);
      s2 += __shfl_xor(s2, m);
    }
    const float mu = s1 * 0.03125f;
    const float var = s2 * 0.03125f - mu * mu;
    const float rs = rsqrtf(var + 1e-5f);
    float4 hv;
    hv.x = silu_f((h0 - mu) * rs * lng[j0]     + lnb[j0]);
    hv.y = silu_f((h1 - mu) * rs * lng[j0 + 1] + lnb[j0 + 1]);
    hv.z = silu_f((h2 - mu) * rs * lng[j0 + 2] + lnb[j0 + 2]);
    hv.w = silu_f((h3 - mu) * rs * lng[j0 + 3] + lnb[j0 + 3]);
    *(float4*)&hf[r * HSTR + j0] = hv;
  }
  __syncthreads();

  // ---------------- phase 2: MFMA over the 512-wide cat block -----------------
  f32x4 acc[2];
  #pragma unroll
  for (int mt = 0; mt < 2; ++mt) acc[mt] = (f32x4){0.f, 0.f, 0.f, 0.f};
  #pragma unroll
  for (int mt = 0; mt < 2; ++mt) {
    const unsigned short* arow = &fused[((mt << 4) + (l & 15)) * LDSTR + kg];
    #pragma unroll
    for (int ks = 0; ks < NKS; ++ks) {
      const bf16x8 a = *(const bf16x8*)(arow + (ks << 5));
      acc[mt] = __builtin_amdgcn_mfma_f32_16x16x32_bf16(a, bfw[ks], acc[mt], 0, 0, 0);
    }
  }
  __syncthreads();   // all MFMA reads done; safe to alias z1 onto the cat tile

  // ---------------- phase 2.5: z1 = silu(cat@W1[32:] + h@W1[:32] + b1) --------
  {
    float w1h[32];                       // loaded now (L2-hot) to cap live VGPRs
    #pragma unroll
    for (int j = 0; j < 32; ++j) w1h[j] = W1[j * 64 + bn];
    const float b1v = b1[bn];
    const int rb = (l >> 4) << 2;
    #pragma unroll
    for (int mt = 0; mt < 2; ++mt) {
      #pragma unroll
      for (int v = 0; v < 4; ++v) {
        const int row = (mt << 4) + rb + v;      // C/D layout: row=(l>>4)*4+reg
        const float* hrow = &hf[row * HSTR];
        float s = acc[mt][v] + b1v;
        #pragma unroll
        for (int j = 0; j < 32; ++j) s = __fmaf_rn(hrow[j], w1h[j], s);
        z1[row * Z1STR + bn] = silu_f(s);
      }
    }
  }
  __syncthreads();

  // ---------------- phase 3: out = silu(z1 @ W2 + b2) -------------------------
  {
    const int r  = t >> 3;            // 8 threads per row
    const int j0 = (t & 7) << 2;      // 4 output cols each
    float a0 = b2[j0], a1 = b2[j0 + 1], a2 = b2[j0 + 2], a3 = b2[j0 + 3];
    const float* zr = &z1[r * Z1STR];
    #pragma unroll 8
    for (int k = 0; k < 64; ++k) {
      const float zv = zr[k];
      const float4 w2v = *(const float4*)(W2 + k * 32 + j0);
      a0 = __fmaf_rn(zv, w2v.x, a0);
      a1 = __fmaf_rn(zv, w2v.y, a1);
      a2 = __fmaf_rn(zv, w2v.z, a2);
      a3 = __fmaf_rn(zv, w2v.w, a3);
    }
    float4 o;
    o.x = silu_f(a0); o.y = silu_f(a1); o.z = silu_f(a2); o.w = silu_f(a3);
    *(float4*)(out + (size_t)(R0 + r) * 32 + j0) = o;
  }
}

extern "C" void kernel_launch(void* const* d_in, const int* in_sizes, int n_in,
                              void* d_out, int out_size, void* d_ws, size_t ws_size,
                              hipStream_t stream) {
  const float* xc   = (const float*)d_in[0];
  const int*   xcat = (const int*)  d_in[1];
  const float* emb  = (const float*)d_in[2];
  const float* Wc   = (const float*)d_in[3];
  const float* bc   = (const float*)d_in[4];
  const float* lng  = (const float*)d_in[5];
  const float* lnb  = (const float*)d_in[6];
  const float* W1   = (const float*)d_in[7];
  const float* b1   = (const float*)d_in[8];
  const float* W2   = (const float*)d_in[9];
  const float* b2   = (const float*)d_in[10];
  float* out = (float*)d_out;

  const int B = in_sizes[0] / 64;        // 131072
  const int grid = B / BROWS;            // 4096
  hipLaunchKernelGGL(tab_fused, dim3(grid), dim3(256), 0, stream,
                     xc, xcat, emb, Wc, bc, lng, lnb, W1, b1, W2, b2, out);
}

// Round 3
// 140.393 us; speedup vs baseline: 1.4495x; 1.4495x over previous
//
#include <hip/hip_runtime.h>

typedef __attribute__((ext_vector_type(8))) short bf16x8;
typedef __attribute__((ext_vector_type(4))) float f32x4;
typedef __attribute__((ext_vector_type(8))) unsigned short u16x8;

#define NT 26
#define BROWS 32
#define NKH 8             // k-steps of 32 per half (2 halves over the 512-wide block)
#define LDSTR 520         // bf16 elems per LDS row (508 cat + 4 zero + 8 slack)
#define HSTR 36           // fp32 h row stride (dwords)
#define Z1STR 68          // fp32 z1 row stride (dwords)

__constant__ int c_OFFS[NT] = {
    0,1000001,1500002,1600003,1650004,1660005,1670006,1675007,1680008,1681009,
    1682010,1682511,1683012,1683113,1683214,1683265,1683316,1683337,1683358,
    1683369,1683380,1683386,1683392,1683396,1683400,1683403};
__constant__ int c_DIMS[NT] = {
    32,32,32,32,32,32,32,32,32,32,32,32,21,21,14,14,9,9,6,6,4,4,4,4,4,4};
__constant__ int c_COLF[NT] = {
    0,32,64,96,128,160,192,224,256,288,320,352,384,405,426,440,454,463,
    472,478,484,488,492,496,500,504};

__device__ __forceinline__ unsigned short f2bf(float f) {
  unsigned int u = __builtin_bit_cast(unsigned int, f);
  u += 0x7fffu + ((u >> 16) & 1u);       // RNE
  return (unsigned short)(u >> 16);
}

__device__ __forceinline__ float silu_f(float x) {
  return x / (1.0f + __expf(-x));
}

__device__ __forceinline__ void load_bfw(const float* __restrict__ W1,
                                         bf16x8* bfw, int half, int kg, int bn) {
  #pragma unroll
  for (int ks = 0; ks < NKH; ++ks) {
    #pragma unroll
    for (int j = 0; j < 8; ++j) {
      const int k = 32 + (half << 8) + (ks << 5) + kg + j;   // global W1 row
      const float v = (k < 540) ? W1[k * 64 + bn] : 0.0f;
      bfw[ks][j] = (short)f2bf(v);
    }
  }
}

__device__ __forceinline__ void gather_one(const float* __restrict__ emb,
                                           unsigned short* __restrict__ fused,
                                           int p, int idx) {
  const int i = p >> 5;          // table id (wave-uniform by construction)
  const int r = p & 31;          // batch row within tile
  const float* src = emb + (size_t)(c_OFFS[i] + idx) * 32;
  unsigned short* dst = &fused[r * LDSTR + c_COLF[i]];
  const int d = c_DIMS[i];
  if (d == 32) {
    const float4* s4 = (const float4*)src;
    const float4 f0 = s4[0], f1 = s4[1], f2 = s4[2], f3 = s4[3];
    const float4 f4 = s4[4], f5 = s4[5], f6 = s4[6], f7 = s4[7];
    u16x8 o0, o1, o2, o3;
    o0[0]=f2bf(f0.x); o0[1]=f2bf(f0.y); o0[2]=f2bf(f0.z); o0[3]=f2bf(f0.w);
    o0[4]=f2bf(f1.x); o0[5]=f2bf(f1.y); o0[6]=f2bf(f1.z); o0[7]=f2bf(f1.w);
    o1[0]=f2bf(f2.x); o1[1]=f2bf(f2.y); o1[2]=f2bf(f2.z); o1[3]=f2bf(f2.w);
    o1[4]=f2bf(f3.x); o1[5]=f2bf(f3.y); o1[6]=f2bf(f3.z); o1[7]=f2bf(f3.w);
    o2[0]=f2bf(f4.x); o2[1]=f2bf(f4.y); o2[2]=f2bf(f4.z); o2[3]=f2bf(f4.w);
    o2[4]=f2bf(f5.x); o2[5]=f2bf(f5.y); o2[6]=f2bf(f5.z); o2[7]=f2bf(f5.w);
    o3[0]=f2bf(f6.x); o3[1]=f2bf(f6.y); o3[2]=f2bf(f6.z); o3[3]=f2bf(f6.w);
    o3[4]=f2bf(f7.x); o3[5]=f2bf(f7.y); o3[6]=f2bf(f7.z); o3[7]=f2bf(f7.w);
    u16x8* d8 = (u16x8*)dst;     // COLF even for d==32 tables; 1040B row stride
    d8[0] = o0; d8[1] = o1; d8[2] = o2; d8[3] = o3;
  } else {
    #pragma unroll 4
    for (int c = 0; c < d; ++c) dst[c] = f2bf(src[c]);
  }
}

extern "C" __global__ void __launch_bounds__(256, 2)
tab_fused(const float* __restrict__ xc,   // [B,64]
          const int* __restrict__ xcat,   // [B,26]
          const float* __restrict__ emb,  // [TOTAL_ROWS,32]
          const float* __restrict__ Wc,   // [64,32]
          const float* __restrict__ bc,   // [32]
          const float* __restrict__ lng,  // [32]
          const float* __restrict__ lnb,  // [32]
          const float* __restrict__ W1,   // [540,64]
          const float* __restrict__ b1,   // [64]
          const float* __restrict__ W2,   // [64,32]
          const float* __restrict__ b2,   // [32]
          float* __restrict__ out) {      // [B,32]
  // cat tile (bf16) lives here during phases 1-2; z1 (fp32) aliases it after.
  __shared__ __attribute__((aligned(16))) float smem[(BROWS * LDSTR) / 2]; // 33,280 B
  __shared__ __attribute__((aligned(16))) float hf[BROWS * HSTR];          //  4,608 B
  unsigned short* fused = (unsigned short*)smem;
  float* z1 = smem;

  const int t  = threadIdx.x;
  const int w  = t >> 6;          // wave id 0..3
  const int l  = t & 63;          // lane
  const int R0 = blockIdx.x * BROWS;

  // ---------------- phase 0: stage W1 half-0 bf16 B-fragments -----------------
  const int bn = (w << 4) + (l & 15);   // z1 column owned by this lane
  const int kg = (l >> 4) << 3;         // k sub-offset 0/8/16/24 within a k-step
  bf16x8 bfw[NKH];                      // only half a panel resident: 32 VGPRs
  load_bfw(W1, bfw, 0, kg, bn);
  // zero pad cols 508..511 (one 8B write per row)
  if (t < BROWS) *(unsigned long long*)&fused[t * LDSTR + 508] = 0ull;

  // ---------------- phase 1a: gather (all 256 threads, table-major) -----------
  // p = i*32 + r: each wave-iteration covers exactly 2 equal-width tables.
  int pidx[4];
  #pragma unroll
  for (int it = 0; it < 3; ++it) {
    const int p = t + it * 256;
    pidx[it] = xcat[(size_t)(R0 + (p & 31)) * NT + (p >> 5)];
  }
  if (t < 64) pidx[3] = xcat[(size_t)(R0 + (t & 31)) * NT + ((t + 768) >> 5)];
  #pragma unroll
  for (int it = 0; it < 3; ++it) gather_one(emb, fused, t + it * 256, pidx[it]);
  if (t < 64) gather_one(emb, fused, t + 768, pidx[3]);

  // ---------------- phase 1b: cont MLP, 8 threads per row ---------------------
  {
    const int r  = t >> 3;
    const int j0 = (t & 7) << 2;
    const float* xr = xc + (size_t)(R0 + r) * 64;
    float h0 = bc[j0], h1 = bc[j0 + 1], h2 = bc[j0 + 2], h3 = bc[j0 + 3];
    #pragma unroll 4
    for (int k4 = 0; k4 < 16; ++k4) {
      const float4 x4 = ((const float4*)xr)[k4];
      const float* wb = Wc + (k4 * 4) * 32 + j0;
      const float4 w0 = *(const float4*)(wb);
      const float4 w1 = *(const float4*)(wb + 32);
      const float4 w2 = *(const float4*)(wb + 64);
      const float4 w3 = *(const float4*)(wb + 96);
      h0 = __fmaf_rn(x4.x, w0.x, h0); h1 = __fmaf_rn(x4.x, w0.y, h1);
      h2 = __fmaf_rn(x4.x, w0.z, h2); h3 = __fmaf_rn(x4.x, w0.w, h3);
      h0 = __fmaf_rn(x4.y, w1.x, h0); h1 = __fmaf_rn(x4.y, w1.y, h1);
      h2 = __fmaf_rn(x4.y, w1.z, h2); h3 = __fmaf_rn(x4.y, w1.w, h3);
      h0 = __fmaf_rn(x4.z, w2.x, h0); h1 = __fmaf_rn(x4.z, w2.y, h1);
      h2 = __fmaf_rn(x4.z, w2.z, h2); h3 = __fmaf_rn(x4.z, w2.w, h3);
      h0 = __fmaf_rn(x4.w, w3.x, h0); h1 = __fmaf_rn(x4.w, w3.y, h1);
      h2 = __fmaf_rn(x4.w, w3.z, h2); h3 = __fmaf_rn(x4.w, w3.w, h3);
    }
    // LayerNorm over the 8-lane group holding this row's 32 outputs
    float s1 = h0 + h1 + h2 + h3;
    float s2 = h0 * h0 + h1 * h1 + h2 * h2 + h3 * h3;
    #pragma unroll
    for (int m = 1; m < 8; m <<= 1) {
      s1 += __shfl_xor(s1, m);
      s2 += __shfl_xor(s2, m);
    }
    const float mu = s1 * 0.03125f;
    const float var = s2 * 0.03125f - mu * mu;
    const float rs = rsqrtf(var + 1e-5f);
    float4 hv;
    hv.x = silu_f((h0 - mu) * rs * lng[j0]     + lnb[j0]);
    hv.y = silu_f((h1 - mu) * rs * lng[j0 + 1] + lnb[j0 + 1]);
    hv.z = silu_f((h2 - mu) * rs * lng[j0 + 2] + lnb[j0 + 2]);
    hv.w = silu_f((h3 - mu) * rs * lng[j0 + 3] + lnb[j0 + 3]);
    *(float4*)&hf[r * HSTR + j0] = hv;
  }
  __syncthreads();

  // ---------------- phase 2: MFMA, two K-halves of 8 steps each ---------------
  f32x4 acc[2];
  acc[0] = (f32x4){0.f, 0.f, 0.f, 0.f};
  acc[1] = (f32x4){0.f, 0.f, 0.f, 0.f};
  const unsigned short* arow0 = &fused[(l & 15) * LDSTR + kg];
  const unsigned short* arow1 = arow0 + 16 * LDSTR;
  // half 0 (bfw already resident)
  #pragma unroll
  for (int ks = 0; ks < NKH; ++ks) {
    acc[0] = __builtin_amdgcn_mfma_f32_16x16x32_bf16(
        *(const bf16x8*)(arow0 + (ks << 5)), bfw[ks], acc[0], 0, 0, 0);
    acc[1] = __builtin_amdgcn_mfma_f32_16x16x32_bf16(
        *(const bf16x8*)(arow1 + (ks << 5)), bfw[ks], acc[1], 0, 0, 0);
  }
  // half 1: reload B-panel (L2-hot) into the same 32 VGPRs, then MFMA
  load_bfw(W1, bfw, 1, kg, bn);
  #pragma unroll
  for (int ks = 0; ks < NKH; ++ks) {
    acc[0] = __builtin_amdgcn_mfma_f32_16x16x32_bf16(
        *(const bf16x8*)(arow0 + 256 + (ks << 5)), bfw[ks], acc[0], 0, 0, 0);
    acc[1] = __builtin_amdgcn_mfma_f32_16x16x32_bf16(
        *(const bf16x8*)(arow1 + 256 + (ks << 5)), bfw[ks], acc[1], 0, 0, 0);
  }
  __syncthreads();   // all MFMA reads done; safe to alias z1 onto the cat tile

  // ---------------- phase 2.5: z1 = silu(cat@W1[32:] + h@W1[:32] + b1) --------
  {
    float w1h[32];                       // loaded now (L2-hot) to cap live VGPRs
    #pragma unroll
    for (int j = 0; j < 32; ++j) w1h[j] = W1[j * 64 + bn];
    const float b1v = b1[bn];
    const int rb = (l >> 4) << 2;
    #pragma unroll
    for (int mt = 0; mt < 2; ++mt) {
      #pragma unroll
      for (int v = 0; v < 4; ++v) {
        const int row = (mt << 4) + rb + v;      // C/D layout: row=(l>>4)*4+reg
        const float* hrow = &hf[row * HSTR];
        float s = acc[mt][v] + b1v;
        #pragma unroll
        for (int j = 0; j < 32; ++j) s = __fmaf_rn(hrow[j], w1h[j], s);
        z1[row * Z1STR + bn] = silu_f(s);
      }
    }
  }
  __syncthreads();

  // ---------------- phase 3: out = silu(z1 @ W2 + b2) -------------------------
  {
    const int r  = t >> 3;            // 8 threads per row
    const int j0 = (t & 7) << 2;      // 4 output cols each
    float a0 = b2[j0], a1 = b2[j0 + 1], a2 = b2[j0 + 2], a3 = b2[j0 + 3];
    const float* zr = &z1[r * Z1STR];
    #pragma unroll 8
    for (int k = 0; k < 64; ++k) {
      const float zv = zr[k];
      const float4 w2v = *(const float4*)(W2 + k * 32 + j0);
      a0 = __fmaf_rn(zv, w2v.x, a0);
      a1 = __fmaf_rn(zv, w2v.y, a1);
      a2 = __fmaf_rn(zv, w2v.z, a2);
      a3 = __fmaf_rn(zv, w2v.w, a3);
    }
    float4 o;
    o.x = silu_f(a0); o.y = silu_f(a1); o.z = silu_f(a2); o.w = silu_f(a3);
    *(float4*)(out + (size_t)(R0 + r) * 32 + j0) = o;
  }
}

extern "C" void kernel_launch(void* const* d_in, const int* in_sizes, int n_in,
                              void* d_out, int out_size, void* d_ws, size_t ws_size,
                              hipStream_t stream) {
  const float* xc   = (const float*)d_in[0];
  const int*   xcat = (const int*)  d_in[1];
  const float* emb  = (const float*)d_in[2];
  const float* Wc   = (const float*)d_in[3];
  const float* bc   = (const float*)d_in[4];
  const float* lng  = (const float*)d_in[5];
  const float* lnb  = (const float*)d_in[6];
  const float* W1   = (const float*)d_in[7];
  const float* b1   = (const float*)d_in[8];
  const float* W2   = (const float*)d_in[9];
  const float* b2   = (const float*)d_in[10];
  float* out = (float*)d_out;

  const int B = in_sizes[0] / 64;        // 131072
  const int grid = B / BROWS;            // 4096
  hipLaunchKernelGGL(tab_fused, dim3(grid), dim3(256), 0, stream,
                     xc, xcat, emb, Wc, bc, lng, lnb, W1, b1, W2, b2, out);
}

// Round 4
// 126.882 us; speedup vs baseline: 1.6038x; 1.1065x over previous
//
#include <hip/hip_runtime.h>

typedef __attribute__((ext_vector_type(8))) short bf16x8;
typedef __attribute__((ext_vector_type(4))) float f32x4;

#define NT 26
#define BROWS 32
#define NKH 9              // k-steps of 32 per half; K total = 576
#define LDSTR 584          // bf16 elems per tile row (576 + 8 slack); 1168 B stride
#define Z1STR 68           // fp32 z1 row stride (dwords)
#define WS_FRAG_DWORDS 18432   // 576/32 ks * 4 waves * 64 lanes * 8 bf16 / 2

// {emb row offset, tile dst col, n float4 groups, 0}
__constant__ int4 c_TAB[NT] = {
    {0,32,8,0},{1000001,64,8,0},{1500002,96,8,0},{1600003,128,8,0},
    {1650004,160,8,0},{1660005,192,8,0},{1670006,224,8,0},{1675007,256,8,0},
    {1680008,288,8,0},{1681009,320,8,0},{1682010,352,8,0},{1682511,384,8,0},
    {1683012,416,6,0},{1683113,440,6,0},{1683214,464,4,0},{1683265,480,4,0},
    {1683316,496,3,0},{1683337,508,3,0},{1683358,520,2,0},{1683369,528,2,0},
    {1683380,536,1,0},{1683386,540,1,0},{1683392,544,1,0},{1683396,548,1,0},
    {1683400,552,1,0},{1683403,556,1,0}};

// prep-kernel tables: padded col starts (within cat block), true dims, true concat offsets
__constant__ int c_P_COLP[NT] = {
    0,32,64,96,128,160,192,224,256,288,320,352,384,408,432,448,464,476,
    488,496,504,508,512,516,520,524};
__constant__ int c_P_DIMS[NT] = {
    32,32,32,32,32,32,32,32,32,32,32,32,21,21,14,14,9,9,6,6,4,4,4,4,4,4};
__constant__ int c_P_COLF[NT] = {
    0,32,64,96,128,160,192,224,256,288,320,352,384,405,426,440,454,463,
    472,478,484,488,492,496,500,504};

__device__ __forceinline__ unsigned short f2bf(float f) {
  unsigned int u = __builtin_bit_cast(unsigned int, f);
  u += 0x7fffu + ((u >> 16) & 1u);       // RNE
  return (unsigned short)(u >> 16);
}

__device__ __forceinline__ unsigned cvtpk(float a, float b) {
  unsigned r;                             // lo = a, hi = b (RNE)
  asm("v_cvt_pk_bf16_f32 %0, %1, %2" : "=v"(r) : "v"(a), "v"(b));
  return r;
}

__device__ __forceinline__ float silu_f(float x) {
  return x / (1.0f + __expf(-x));
}

// ---- prep: W1 (fp32 [540][64]) -> bf16 MFMA B-fragments in ws ---------------
// frag order: bf16 index f = ((ks*4 + w)*64 + l)*8 + j ; tile-k = ks*32+(l>>4)*8+j
extern "C" __global__ void __launch_bounds__(256)
prep_w1(const float* __restrict__ W1, unsigned int* __restrict__ wsf) {
  const int g = blockIdx.x * 256 + threadIdx.x;   // output dword index
  if (g >= WS_FRAG_DWORDS) return;
  const int f  = g * 2;
  const int j  = f & 7;
  const int l  = (f >> 3) & 63;
  const int w  = (f >> 9) & 3;
  const int ks = f >> 11;
  const int bn = (w << 4) + (l & 15);
  const int k0 = (ks << 5) + ((l >> 4) << 3) + j;
  float v[2];
  #pragma unroll
  for (int e = 0; e < 2; ++e) {
    const int k = k0 + e;
    float x = 0.0f;
    if (k < 32) {
      x = W1[k * 64 + bn];                 // h block: W1 rows 0..31
    } else {
      const int c = k - 32;                // padded cat col
      for (int i = 0; i < NT; ++i) {
        const int off = c - c_P_COLP[i];
        if (off >= 0 && off < c_P_DIMS[i])
          x = W1[(32 + c_P_COLF[i] + off) * 64 + bn];
      }                                    // pad cols & c>=528 stay 0
    }
    v[e] = x;
  }
  wsf[g] = ((unsigned)f2bf(v[0])) | (((unsigned)f2bf(v[1])) << 16);
}

// ---- gather one (row, table) into the bf16 tile -----------------------------
__device__ __forceinline__ void gather_one(const float* __restrict__ emb,
                                           unsigned short* __restrict__ fused,
                                           int p, int idx) {
  const int i = p >> 5;          // table (uniform per half-wave)
  const int r = p & 31;          // batch row within tile
  const int4 tb = c_TAB[i];
  const float4* src = (const float4*)(emb + (size_t)(tb.x + idx) * 32);
  char* dstb = (char*)fused + r * (LDSTR * 2) + tb.y * 2;
  if (tb.z == 8) {
    const float4 f0 = src[0], f1 = src[1], f2 = src[2], f3 = src[3];
    const float4 f4 = src[4], f5 = src[5], f6 = src[6], f7 = src[7];
    uint4 o0, o1, o2, o3;
    o0.x = cvtpk(f0.x, f0.y); o0.y = cvtpk(f0.z, f0.w);
    o0.z = cvtpk(f1.x, f1.y); o0.w = cvtpk(f1.z, f1.w);
    o1.x = cvtpk(f2.x, f2.y); o1.y = cvtpk(f2.z, f2.w);
    o1.z = cvtpk(f3.x, f3.y); o1.w = cvtpk(f3.z, f3.w);
    o2.x = cvtpk(f4.x, f4.y); o2.y = cvtpk(f4.z, f4.w);
    o2.z = cvtpk(f5.x, f5.y); o2.w = cvtpk(f5.z, f5.w);
    o3.x = cvtpk(f6.x, f6.y); o3.y = cvtpk(f6.z, f6.w);
    o3.z = cvtpk(f7.x, f7.y); o3.w = cvtpk(f7.z, f7.w);
    uint4* d4 = (uint4*)dstb;              // 16B aligned (dstcol*2 % 16 == 0)
    d4[0] = o0; d4[1] = o1; d4[2] = o2; d4[3] = o3;
  } else {
    // narrow tables: write ceil(d/4)*4 cols; pad-col garbage is finite and
    // multiplied by ZERO W1-fragment rows in the MFMA, so no masking needed.
    uint2* d2 = (uint2*)dstb;              // 8B aligned (dstcol % 4 == 0)
    for (int c4 = 0; c4 < tb.z; ++c4) {
      const float4 fv = src[c4];
      uint2 o;
      o.x = cvtpk(fv.x, fv.y);
      o.y = cvtpk(fv.z, fv.w);
      d2[c4] = o;
    }
  }
}

extern "C" __global__ void __launch_bounds__(256, 2)
tab_fused(const float* __restrict__ xc,   // [B,64]
          const int* __restrict__ xcat,   // [B,26]
          const float* __restrict__ emb,  // [TOTAL_ROWS,32]
          const float* __restrict__ Wc,   // [64,32]
          const float* __restrict__ bc,   // [32]
          const float* __restrict__ lng,  // [32]
          const float* __restrict__ lnb,  // [32]
          const unsigned short* __restrict__ wsf,  // W1 bf16 fragments
          const float* __restrict__ b1,   // [64]
          const float* __restrict__ W2,   // [64,32]
          const float* __restrict__ b2,   // [32]
          float* __restrict__ out) {      // [B,32]
  // bf16 tile [32][LDSTR] during phases 1-2; z1 (fp32 [32][Z1STR]) aliases after.
  __shared__ __attribute__((aligned(16))) float smem[(BROWS * LDSTR) / 2]; // 37,376 B
  unsigned short* fused = (unsigned short*)smem;
  float* z1 = smem;

  const int t  = threadIdx.x;
  const int w  = t >> 6;          // wave id 0..3
  const int l  = t & 63;          // lane
  const int R0 = blockIdx.x * BROWS;

  const int bn = (w << 4) + (l & 15);   // z1 column owned by this lane
  const int kg = (l >> 4) << 3;         // k sub-offset within a k-step

  // ---------------- phase 0: B-fragment half 0 from ws (coalesced) ------------
  bf16x8 bfw[NKH];
  #pragma unroll
  for (int ks = 0; ks < NKH; ++ks)
    bfw[ks] = *(const bf16x8*)(wsf + (((ks) * 4 + w) * 64 + l) * 8);
  // zero never-written cols 560..575 (avoid NaN bit patterns in LDS)
  if (t < 64) {
    uint4 zz = {0u, 0u, 0u, 0u};
    *(uint4*)((char*)fused + (t >> 1) * (LDSTR * 2) + (560 + (t & 1) * 8) * 2) = zz;
  }

  // ---------------- phase 1a: gather (all 256 threads, table-major) -----------
  int pidx[4];
  #pragma unroll
  for (int it = 0; it < 3; ++it) {
    const int p = t + it * 256;
    pidx[it] = xcat[(size_t)(R0 + (p & 31)) * NT + (p >> 5)];
  }
  if (t < 64) pidx[3] = xcat[(size_t)(R0 + (t & 31)) * NT + ((t + 768) >> 5)];
  #pragma unroll
  for (int it = 0; it < 3; ++it) gather_one(emb, fused, t + it * 256, pidx[it]);
  if (t < 64) gather_one(emb, fused, t + 768, pidx[3]);

  // ---------------- phase 1b: cont MLP -> bf16 into tile cols 0..31 -----------
  {
    const int r  = t >> 3;
    const int j0 = (t & 7) << 2;
    const float* xr = xc + (size_t)(R0 + r) * 64;
    float h0 = bc[j0], h1 = bc[j0 + 1], h2 = bc[j0 + 2], h3 = bc[j0 + 3];
    #pragma unroll 4
    for (int k4 = 0; k4 < 16; ++k4) {
      const float4 x4 = ((const float4*)xr)[k4];
      const float* wb = Wc + (k4 * 4) * 32 + j0;
      const float4 w0 = *(const float4*)(wb);
      const float4 w1 = *(const float4*)(wb + 32);
      const float4 w2 = *(const float4*)(wb + 64);
      const float4 w3 = *(const float4*)(wb + 96);
      h0 = __fmaf_rn(x4.x, w0.x, h0); h1 = __fmaf_rn(x4.x, w0.y, h1);
      h2 = __fmaf_rn(x4.x, w0.z, h2); h3 = __fmaf_rn(x4.x, w0.w, h3);
      h0 = __fmaf_rn(x4.y, w1.x, h0); h1 = __fmaf_rn(x4.y, w1.y, h1);
      h2 = __fmaf_rn(x4.y, w1.z, h2); h3 = __fmaf_rn(x4.y, w1.w, h3);
      h0 = __fmaf_rn(x4.z, w2.x, h0); h1 = __fmaf_rn(x4.z, w2.y, h1);
      h2 = __fmaf_rn(x4.z, w2.z, h2); h3 = __fmaf_rn(x4.z, w2.w, h3);
      h0 = __fmaf_rn(x4.w, w3.x, h0); h1 = __fmaf_rn(x4.w, w3.y, h1);
      h2 = __fmaf_rn(x4.w, w3.z, h2); h3 = __fmaf_rn(x4.w, w3.w, h3);
    }
    float s1 = h0 + h1 + h2 + h3;
    float s2 = h0 * h0 + h1 * h1 + h2 * h2 + h3 * h3;
    #pragma unroll
    for (int m = 1; m < 8; m <<= 1) {
      s1 += __shfl_xor(s1, m);
      s2 += __shfl_xor(s2, m);
    }
    const float mu = s1 * 0.03125f;
    const float var = s2 * 0.03125f - mu * mu;
    const float rs = rsqrtf(var + 1e-5f);
    const float g0 = silu_f((h0 - mu) * rs * lng[j0]     + lnb[j0]);
    const float g1 = silu_f((h1 - mu) * rs * lng[j0 + 1] + lnb[j0 + 1]);
    const float g2 = silu_f((h2 - mu) * rs * lng[j0 + 2] + lnb[j0 + 2]);
    const float g3 = silu_f((h3 - mu) * rs * lng[j0 + 3] + lnb[j0 + 3]);
    uint2 hw;
    hw.x = cvtpk(g0, g1);
    hw.y = cvtpk(g2, g3);
    *(uint2*)((char*)fused + r * (LDSTR * 2) + j0 * 2) = hw;
  }
  __syncthreads();

  // ---------------- phase 2: MFMA over K=576, two halves ----------------------
  f32x4 acc[2];
  acc[0] = (f32x4){0.f, 0.f, 0.f, 0.f};
  acc[1] = (f32x4){0.f, 0.f, 0.f, 0.f};
  const unsigned short* arow0 = &fused[(l & 15) * LDSTR + kg];
  const unsigned short* arow1 = arow0 + 16 * LDSTR;
  #pragma unroll
  for (int ks = 0; ks < NKH; ++ks) {
    acc[0] = __builtin_amdgcn_mfma_f32_16x16x32_bf16(
        *(const bf16x8*)(arow0 + (ks << 5)), bfw[ks], acc[0], 0, 0, 0);
    acc[1] = __builtin_amdgcn_mfma_f32_16x16x32_bf16(
        *(const bf16x8*)(arow1 + (ks << 5)), bfw[ks], acc[1], 0, 0, 0);
  }
  #pragma unroll
  for (int ks = 0; ks < NKH; ++ks)
    bfw[ks] = *(const bf16x8*)(wsf + (((NKH + ks) * 4 + w) * 64 + l) * 8);
  #pragma unroll
  for (int ks = 0; ks < NKH; ++ks) {
    acc[0] = __builtin_amdgcn_mfma_f32_16x16x32_bf16(
        *(const bf16x8*)(arow0 + 288 + (ks << 5)), bfw[ks], acc[0], 0, 0, 0);
    acc[1] = __builtin_amdgcn_mfma_f32_16x16x32_bf16(
        *(const bf16x8*)(arow1 + 288 + (ks << 5)), bfw[ks], acc[1], 0, 0, 0);
  }
  __syncthreads();   // all MFMA reads done; safe to alias z1 onto the tile

  // ---------------- phase 2.5: z1 = silu(acc + b1) ----------------------------
  {
    const float b1v = b1[bn];
    const int rb = (l >> 4) << 2;
    #pragma unroll
    for (int mt = 0; mt < 2; ++mt) {
      #pragma unroll
      for (int v = 0; v < 4; ++v) {
        const int row = (mt << 4) + rb + v;      // C/D layout: row=(l>>4)*4+reg
        z1[row * Z1STR + bn] = silu_f(acc[mt][v] + b1v);
      }
    }
  }
  __syncthreads();

  // ---------------- phase 3: out = silu(z1 @ W2 + b2) -------------------------
  {
    const int r  = t >> 3;            // 8 threads per row
    const int j0 = (t & 7) << 2;      // 4 output cols each
    float a0 = b2[j0], a1 = b2[j0 + 1], a2 = b2[j0 + 2], a3 = b2[j0 + 3];
    const float* zr = &z1[r * Z1STR];
    #pragma unroll 8
    for (int k = 0; k < 64; ++k) {
      const float zv = zr[k];
      const float4 w2v = *(const float4*)(W2 + k * 32 + j0);
      a0 = __fmaf_rn(zv, w2v.x, a0);
      a1 = __fmaf_rn(zv, w2v.y, a1);
      a2 = __fmaf_rn(zv, w2v.z, a2);
      a3 = __fmaf_rn(zv, w2v.w, a3);
    }
    float4 o;
    o.x = silu_f(a0); o.y = silu_f(a1); o.z = silu_f(a2); o.w = silu_f(a3);
    *(float4*)(out + (size_t)(R0 + r) * 32 + j0) = o;
  }
}

extern "C" void kernel_launch(void* const* d_in, const int* in_sizes, int n_in,
                              void* d_out, int out_size, void* d_ws, size_t ws_size,
                              hipStream_t stream) {
  const float* xc   = (const float*)d_in[0];
  const int*   xcat = (const int*)  d_in[1];
  const float* emb  = (const float*)d_in[2];
  const float* Wc   = (const float*)d_in[3];
  const float* bc   = (const float*)d_in[4];
  const float* lng  = (const float*)d_in[5];
  const float* lnb  = (const float*)d_in[6];
  const float* W1   = (const float*)d_in[7];
  const float* b1   = (const float*)d_in[8];
  const float* W2   = (const float*)d_in[9];
  const float* b2   = (const float*)d_in[10];
  float* out = (float*)d_out;

  unsigned int* wsf = (unsigned int*)d_ws;     // 73,728 B of W1 fragments
  hipLaunchKernelGGL(prep_w1, dim3((WS_FRAG_DWORDS + 255) / 256), dim3(256),
                     0, stream, W1, wsf);

  const int B = in_sizes[0] / 64;        // 131072
  const int grid = B / BROWS;            // 4096
  hipLaunchKernelGGL(tab_fused, dim3(grid), dim3(256), 0, stream,
                     xc, xcat, emb, Wc, bc, lng, lnb,
                     (const unsigned short*)wsf, b1, W2, b2, out);
}

// Round 5
// 125.924 us; speedup vs baseline: 1.6160x; 1.0076x over previous
//
#include <hip/hip_runtime.h>

typedef __attribute__((ext_vector_type(8))) short bf16x8;
typedef __attribute__((ext_vector_type(4))) float f32x4;

#define NT 26
#define BROWS 32
#define NKS 18             // k-steps of 32; K total = 576
#define LDSTR 584          // bf16 elems per tile row (576 + 8 slack); 1168 B stride
#define Z1STR 68           // fp32 z1 row stride (dwords)
#define WS_FRAG_DWORDS 18432   // 18 ks * 4 waves * 64 lanes * 8 bf16 / 2

// {emb row offset, tile dst col, n float4 groups, 0}
__constant__ int4 c_TAB[NT] = {
    {0,32,8,0},{1000001,64,8,0},{1500002,96,8,0},{1600003,128,8,0},
    {1650004,160,8,0},{1660005,192,8,0},{1670006,224,8,0},{1675007,256,8,0},
    {1680008,288,8,0},{1681009,320,8,0},{1682010,352,8,0},{1682511,384,8,0},
    {1683012,416,6,0},{1683113,440,6,0},{1683214,464,4,0},{1683265,480,4,0},
    {1683316,496,3,0},{1683337,508,3,0},{1683358,520,2,0},{1683369,528,2,0},
    {1683380,536,1,0},{1683386,540,1,0},{1683392,544,1,0},{1683396,548,1,0},
    {1683400,552,1,0},{1683403,556,1,0}};

// prep-kernel tables: padded col starts (within cat block), true dims, true concat offsets
__constant__ int c_P_COLP[NT] = {
    0,32,64,96,128,160,192,224,256,288,320,352,384,408,432,448,464,476,
    488,496,504,508,512,516,520,524};
__constant__ int c_P_DIMS[NT] = {
    32,32,32,32,32,32,32,32,32,32,32,32,21,21,14,14,9,9,6,6,4,4,4,4,4,4};
__constant__ int c_P_COLF[NT] = {
    0,32,64,96,128,160,192,224,256,288,320,352,384,405,426,440,454,463,
    472,478,484,488,492,496,500,504};

__device__ __forceinline__ unsigned short f2bf(float f) {
  unsigned int u = __builtin_bit_cast(unsigned int, f);
  u += 0x7fffu + ((u >> 16) & 1u);       // RNE
  return (unsigned short)(u >> 16);
}

__device__ __forceinline__ unsigned cvtpk(float a, float b) {
  unsigned r;                             // lo = a, hi = b (RNE)
  asm("v_cvt_pk_bf16_f32 %0, %1, %2" : "=v"(r) : "v"(a), "v"(b));
  return r;
}

__device__ __forceinline__ uint4 pk4(float4 a, float4 b) {
  uint4 o;
  o.x = cvtpk(a.x, a.y); o.y = cvtpk(a.z, a.w);
  o.z = cvtpk(b.x, b.y); o.w = cvtpk(b.z, b.w);
  return o;
}

__device__ __forceinline__ uint2 pk2(float4 a) {
  uint2 o;
  o.x = cvtpk(a.x, a.y); o.y = cvtpk(a.z, a.w);
  return o;
}

__device__ __forceinline__ float silu_f(float x) {
  return x / (1.0f + __expf(-x));
}

// ---- prep: W1 (fp32 [540][64]) -> bf16 MFMA B-fragments in ws ---------------
// frag order: bf16 index f = ((ks*4 + w)*64 + l)*8 + j ; tile-k = ks*32+(l>>4)*8+j
extern "C" __global__ void __launch_bounds__(256)
prep_w1(const float* __restrict__ W1, unsigned int* __restrict__ wsf) {
  const int g = blockIdx.x * 256 + threadIdx.x;   // output dword index
  if (g >= WS_FRAG_DWORDS) return;
  const int f  = g * 2;
  const int j  = f & 7;
  const int l  = (f >> 3) & 63;
  const int w  = (f >> 9) & 3;
  const int ks = f >> 11;
  const int bn = (w << 4) + (l & 15);
  const int k0 = (ks << 5) + ((l >> 4) << 3) + j;
  float v[2];
  #pragma unroll
  for (int e = 0; e < 2; ++e) {
    const int k = k0 + e;
    float x = 0.0f;
    if (k < 32) {
      x = W1[k * 64 + bn];                 // h block: W1 rows 0..31
    } else {
      const int c = k - 32;                // padded cat col
      for (int i = 0; i < NT; ++i) {
        const int off = c - c_P_COLP[i];
        if (off >= 0 && off < c_P_DIMS[i])
          x = W1[(32 + c_P_COLF[i] + off) * 64 + bn];
      }                                    // pad cols & c>=528 stay 0
    }
    v[e] = x;
  }
  wsf[g] = ((unsigned)f2bf(v[0])) | (((unsigned)f2bf(v[1])) << 16);
}

extern "C" __global__ void __launch_bounds__(256, 2)
tab_fused(const float* __restrict__ xc,   // [B,64]
          const int* __restrict__ xcat,   // [B,26]
          const float* __restrict__ emb,  // [TOTAL_ROWS,32]
          const float* __restrict__ Wc,   // [64,32]
          const float* __restrict__ bc,   // [32]
          const float* __restrict__ lng,  // [32]
          const float* __restrict__ lnb,  // [32]
          const unsigned short* __restrict__ wsf,  // W1 bf16 fragments
          const float* __restrict__ b1,   // [64]
          const float* __restrict__ W2,   // [64,32]
          const float* __restrict__ b2,   // [32]
          float* __restrict__ out) {      // [B,32]
  // bf16 tile [32][LDSTR] during phases 1-2; z1 (fp32 [32][Z1STR]) aliases after.
  __shared__ __attribute__((aligned(16))) float smem[(BROWS * LDSTR) / 2]; // 37,376 B
  unsigned short* fused = (unsigned short*)smem;
  float* z1 = smem;

  const int t  = threadIdx.x;
  const int w  = t >> 6;          // wave id 0..3
  const int l  = t & 63;          // lane
  const int R0 = blockIdx.x * BROWS;

  const int bn = (w << 4) + (l & 15);   // z1 column owned by this lane
  const int kg = (l >> 4) << 3;         // k sub-offset within a k-step

  // ---------------- phase 1a: gather — batch-issue ALL loads ------------------
  // Table-major: thread t covers (table t>>5 + {0,8,16}, row t&31), plus
  // tables 24/25 for t<64. Every emb row has 32 floats, so full-quad loads
  // are always in-bounds; pad-col garbage is annihilated by zero W1 rows.
  const int r_ = t & 31;
  const int i0 = t >> 5;
  const bool has3 = (t < 64);
  const int i3 = 24 + (t >> 5);          // only meaningful when has3
  const int* xrow = xcat + (size_t)(R0 + r_) * NT;
  const int idx0 = xrow[i0];
  const int idx1 = xrow[i0 + 8];
  const int idx2 = xrow[i0 + 16];
  const int idx3 = has3 ? xrow[i3] : 0;

  const int4 tb0 = c_TAB[i0];
  const int4 tb1 = c_TAB[i0 + 8];
  const int4 tb2 = c_TAB[i0 + 16];
  const int4 tb3 = c_TAB[has3 ? i3 : 24];

  const float4* s0 = (const float4*)(emb + (size_t)(tb0.x + idx0) * 32);
  const float4* s1 = (const float4*)(emb + (size_t)(tb1.x + idx1) * 32);
  const float4* s2 = (const float4*)(emb + (size_t)(tb2.x + idx2) * 32);
  const float4* s3 = (const float4*)(emb + (size_t)(tb3.x + idx3) * 32);

  const float4 A0 = s0[0], A1 = s0[1], A2 = s0[2], A3 = s0[3];
  const float4 A4 = s0[4], A5 = s0[5], A6 = s0[6], A7 = s0[7];
  const float4 B0 = s1[0], B1 = s1[1], B2 = s1[2], B3 = s1[3];
  const float4 B4 = s1[4], B5 = s1[5], B6 = s1[6], B7 = s1[7];
  const float4 C0 = s2[0], C1 = s2[1], C2 = s2[2];
  float4 D0;
  if (has3) D0 = s3[0];

  // zero never-written cols 560..575 (avoid NaN bit patterns in LDS)
  if (t < 64) {
    uint4 zz = {0u, 0u, 0u, 0u};
    *(uint4*)((char*)fused + (t >> 1) * (LDSTR * 2) + (560 + (t & 1) * 8) * 2) = zz;
  }

  // convert + store (batch write-late)
  char* rowb = (char*)fused + r_ * (LDSTR * 2);
  {
    uint4* d4 = (uint4*)(rowb + tb0.y * 2);            // always 8 quads
    d4[0] = pk4(A0, A1); d4[1] = pk4(A2, A3);
    d4[2] = pk4(A4, A5); d4[3] = pk4(A6, A7);
  }
  {
    uint4* d4 = (uint4*)(rowb + tb1.y * 2);            // z in {4,6,8}
    d4[0] = pk4(B0, B1); d4[1] = pk4(B2, B3);
    if (tb1.z >= 6) d4[2] = pk4(B4, B5);
    if (tb1.z == 8) d4[3] = pk4(B6, B7);
  }
  {
    uint2* d2 = (uint2*)(rowb + tb2.y * 2);            // z in {1,2,3}
    d2[0] = pk2(C0);
    if (tb2.z >= 2) d2[1] = pk2(C1);
    if (tb2.z == 3) d2[2] = pk2(C2);
  }
  if (has3) {
    uint2* d2 = (uint2*)(rowb + tb3.y * 2);            // z == 1
    d2[0] = pk2(D0);
  }

  // ---------------- phase 1b: cont MLP -> bf16 into tile cols 0..31 -----------
  {
    const int r  = t >> 3;
    const int j0 = (t & 7) << 2;
    const float* xr = xc + (size_t)(R0 + r) * 64;
    float h0 = bc[j0], h1 = bc[j0 + 1], h2 = bc[j0 + 2], h3 = bc[j0 + 3];
    #pragma unroll 4
    for (int k4 = 0; k4 < 16; ++k4) {
      const float4 x4 = ((const float4*)xr)[k4];
      const float* wb = Wc + (k4 * 4) * 32 + j0;
      const float4 w0 = *(const float4*)(wb);
      const float4 w1 = *(const float4*)(wb + 32);
      const float4 w2 = *(const float4*)(wb + 64);
      const float4 w3 = *(const float4*)(wb + 96);
      h0 = __fmaf_rn(x4.x, w0.x, h0); h1 = __fmaf_rn(x4.x, w0.y, h1);
      h2 = __fmaf_rn(x4.x, w0.z, h2); h3 = __fmaf_rn(x4.x, w0.w, h3);
      h0 = __fmaf_rn(x4.y, w1.x, h0); h1 = __fmaf_rn(x4.y, w1.y, h1);
      h2 = __fmaf_rn(x4.y, w1.z, h2); h3 = __fmaf_rn(x4.y, w1.w, h3);
      h0 = __fmaf_rn(x4.z, w2.x, h0); h1 = __fmaf_rn(x4.z, w2.y, h1);
      h2 = __fmaf_rn(x4.z, w2.z, h2); h3 = __fmaf_rn(x4.z, w2.w, h3);
      h0 = __fmaf_rn(x4.w, w3.x, h0); h1 = __fmaf_rn(x4.w, w3.y, h1);
      h2 = __fmaf_rn(x4.w, w3.z, h2); h3 = __fmaf_rn(x4.w, w3.w, h3);
    }
    float s1v = h0 + h1 + h2 + h3;
    float s2v = h0 * h0 + h1 * h1 + h2 * h2 + h3 * h3;
    #pragma unroll
    for (int m = 1; m < 8; m <<= 1) {
      s1v += __shfl_xor(s1v, m);
      s2v += __shfl_xor(s2v, m);
    }
    const float mu = s1v * 0.03125f;
    const float var = s2v * 0.03125f - mu * mu;
    const float rs = rsqrtf(var + 1e-5f);
    const float g0 = silu_f((h0 - mu) * rs * lng[j0]     + lnb[j0]);
    const float g1 = silu_f((h1 - mu) * rs * lng[j0 + 1] + lnb[j0 + 1]);
    const float g2 = silu_f((h2 - mu) * rs * lng[j0 + 2] + lnb[j0 + 2]);
    const float g3 = silu_f((h3 - mu) * rs * lng[j0 + 3] + lnb[j0 + 3]);
    uint2 hw;
    hw.x = cvtpk(g0, g1);
    hw.y = cvtpk(g2, g3);
    *(uint2*)((char*)fused + r * (LDSTR * 2) + j0 * 2) = hw;
  }

  // ---------------- phase 0 (late): ALL 18 B-fragment k-steps from ws ---------
  // Issued before the barrier so they drain while waves wait.
  bf16x8 bfw[NKS];
  #pragma unroll
  for (int ks = 0; ks < NKS; ++ks)
    bfw[ks] = *(const bf16x8*)(wsf + ((ks * 4 + w) * 64 + l) * 8);
  __syncthreads();

  // ---------------- phase 2: MFMA over K=576 ----------------------------------
  f32x4 acc[2];
  acc[0] = (f32x4){0.f, 0.f, 0.f, 0.f};
  acc[1] = (f32x4){0.f, 0.f, 0.f, 0.f};
  const unsigned short* arow0 = &fused[(l & 15) * LDSTR + kg];
  const unsigned short* arow1 = arow0 + 16 * LDSTR;
  #pragma unroll
  for (int ks = 0; ks < NKS; ++ks) {
    acc[0] = __builtin_amdgcn_mfma_f32_16x16x32_bf16(
        *(const bf16x8*)(arow0 + (ks << 5)), bfw[ks], acc[0], 0, 0, 0);
    acc[1] = __builtin_amdgcn_mfma_f32_16x16x32_bf16(
        *(const bf16x8*)(arow1 + (ks << 5)), bfw[ks], acc[1], 0, 0, 0);
  }
  __syncthreads();   // all MFMA reads done; safe to alias z1 onto the tile

  // ---------------- phase 2.5: z1 = silu(acc + b1) ----------------------------
  {
    const float b1v = b1[bn];
    const int rb = (l >> 4) << 2;
    #pragma unroll
    for (int mt = 0; mt < 2; ++mt) {
      #pragma unroll
      for (int v = 0; v < 4; ++v) {
        const int row = (mt << 4) + rb + v;      // C/D layout: row=(l>>4)*4+reg
        z1[row * Z1STR + bn] = silu_f(acc[mt][v] + b1v);
      }
    }
  }
  __syncthreads();

  // ---------------- phase 3: out = silu(z1 @ W2 + b2) -------------------------
  {
    const int r  = t >> 3;            // 8 threads per row
    const int j0 = (t & 7) << 2;      // 4 output cols each
    float a0 = b2[j0], a1 = b2[j0 + 1], a2 = b2[j0 + 2], a3 = b2[j0 + 3];
    const float4* zr4 = (const float4*)&z1[r * Z1STR];
    #pragma unroll
    for (int k4 = 0; k4 < 16; ++k4) {
      const float4 zv = zr4[k4];
      const float* w2b = W2 + (k4 * 4) * 32 + j0;
      const float4 w0 = *(const float4*)(w2b);
      const float4 w1 = *(const float4*)(w2b + 32);
      const float4 w2v = *(const float4*)(w2b + 64);
      const float4 w3 = *(const float4*)(w2b + 96);
      a0 = __fmaf_rn(zv.x, w0.x, a0); a1 = __fmaf_rn(zv.x, w0.y, a1);
      a2 = __fmaf_rn(zv.x, w0.z, a2); a3 = __fmaf_rn(zv.x, w0.w, a3);
      a0 = __fmaf_rn(zv.y, w1.x, a0); a1 = __fmaf_rn(zv.y, w1.y, a1);
      a2 = __fmaf_rn(zv.y, w1.z, a2); a3 = __fmaf_rn(zv.y, w1.w, a3);
      a0 = __fmaf_rn(zv.z, w2v.x, a0); a1 = __fmaf_rn(zv.z, w2v.y, a1);
      a2 = __fmaf_rn(zv.z, w2v.z, a2); a3 = __fmaf_rn(zv.z, w2v.w, a3);
      a0 = __fmaf_rn(zv.w, w3.x, a0); a1 = __fmaf_rn(zv.w, w3.y, a1);
      a2 = __fmaf_rn(zv.w, w3.z, a2); a3 = __fmaf_rn(zv.w, w3.w, a3);
    }
    float4 o;
    o.x = silu_f(a0); o.y = silu_f(a1); o.z = silu_f(a2); o.w = silu_f(a3);
    *(float4*)(out + (size_t)(R0 + r) * 32 + j0) = o;
  }
}

extern "C" void kernel_launch(void* const* d_in, const int* in_sizes, int n_in,
                              void* d_out, int out_size, void* d_ws, size_t ws_size,
                              hipStream_t stream) {
  const float* xc   = (const float*)d_in[0];
  const int*   xcat = (const int*)  d_in[1];
  const float* emb  = (const float*)d_in[2];
  const float* Wc   = (const float*)d_in[3];
  const float* bc   = (const float*)d_in[4];
  const float* lng  = (const float*)d_in[5];
  const float* lnb  = (const float*)d_in[6];
  const float* W1   = (const float*)d_in[7];
  const float* b1   = (const float*)d_in[8];
  const float* W2   = (const float*)d_in[9];
  const float* b2   = (const float*)d_in[10];
  float* out = (float*)d_out;

  unsigned int* wsf = (unsigned int*)d_ws;     // 73,728 B of W1 fragments
  hipLaunchKernelGGL(prep_w1, dim3((WS_FRAG_DWORDS + 255) / 256), dim3(256),
                     0, stream, W1, wsf);

  const int B = in_sizes[0] / 64;        // 131072
  const int grid = B / BROWS;            // 4096
  hipLaunchKernelGGL(tab_fused, dim3(grid), dim3(256), 0, stream,
                     xc, xcat, emb, Wc, bc, lng, lnb,
                     (const unsigned short*)wsf, b1, W2, b2, out);
}